// Round 12
// baseline (429.723 us; speedup 1.0000x reference)
//
#include <hip/hip_runtime.h>

// DissipativeRINN — TRANSPOSED fp16 MFMA (M=w-elements, N=batch rows) with
// own-chunk-in-register exchange.
// 128 blocks x 4 waves (256 thr); block = 16 batch rows; wave w owns M-tiles
// 2w,2w+1. eperm identity: a wave's packed tanh output IS B-chunk w — kept in
// registers (f0); only 3 foreign chunks round-trip through LDS per iteration.
// Fragment arrays are chunk-ROTATED (slot i <-> chunk (w+i)&3) so the MFMA
// chain leads with the wait-free own chunk and consumes foreign chunks in
// read-arrival order. One barrier per iteration, double-buffered exchange.

typedef _Float16 f16x8 __attribute__((ext_vector_type(8)));
typedef float f32x4 __attribute__((ext_vector_type(4)));
typedef int i32x4 __attribute__((ext_vector_type(4)));

constexpr int B_TOT   = 2048;
constexpr int T_STEPS = 32;
constexpr int IN_D    = 16;
constexpr int ST_D    = 16;
constexpr int NL_D    = 128;
constexpr int OUT_D   = 8;
constexpr int H_D     = 64;
constexpr int OUT_C   = 17;
constexpr float DT_F  = 0.01f;
constexpr float SC    = 2.8853900817779268f;   // 2*log2(e)

// k-position p = 32s + 8g + j  <->  w-element e (bijective; bit-disjoint)
__device__ __forceinline__ int eperm(int s, int g, int j) {
    return 32 * s + 16 * (j >> 2) + 4 * g + (j & 3);
}

#define MFMA16(A, B, C) __builtin_amdgcn_mfma_f32_16x16x32_f16((A), (B), (C), 0, 0, 0)
#define PK(a, b) __builtin_bit_cast(int, __builtin_amdgcn_cvt_pkrtz((a), (b)))

__global__ __launch_bounds__(256, 1) void rinn_fpi(
    const float* __restrict__ obs, const float* __restrict__ x0,
    const float* __restrict__ A_T, const float* __restrict__ Bw_T,
    const float* __restrict__ By_T, const float* __restrict__ Cv_T,
    const float* __restrict__ Dvw_T, const float* __restrict__ Dvy_T,
    const float* __restrict__ Cu_T, const float* __restrict__ Duw_T,
    const float* __restrict__ Duy_T, float* __restrict__ out)
{
    __shared__ __align__(16) char xch[2][4][1024];   // [dbuf][chunk][lane*16B]
    const int tid  = threadIdx.x;
    const int wid  = tid >> 6;                 // owns M-tiles 2wid,2wid+1 = chunk wid
    const int lane = tid & 63;
    const int g    = lane >> 4;
    const int r16  = lane & 15;
    const int row  = blockIdx.x * 16 + r16;    // this lane's batch row
    const f32x4 z4 = {0.f, 0.f, 0.f, 0.f};

    // rotated chunk ids: slot i handles chunk (wid+i)&3 (slot 0 = own)
    const int c1 = (wid + 1) & 3, c2 = (wid + 2) & 3, c3 = (wid + 3) & 3;

    // ---- A fragments, chunk-rotated. Dvw_T[in][out], SC pre-scaled ----
    f16x8 aD[2][4];                            // [tile n][slot i]
#pragma unroll
    for (int n = 0; n < 2; ++n)
#pragma unroll
        for (int i = 0; i < 4; ++i) {
            const int s = (wid + i) & 3;
            f16x8 h;
#pragma unroll
            for (int j = 0; j < 8; ++j)
                h[j] = (_Float16)(SC * Dvw_T[eperm(s, g, j) * NL_D + 16 * (2 * wid + n) + r16]);
            aD[n][i] = h;
        }
    f16x8 aB[2];                               // [Cv;Dvy] over xy (K=32), x SC
#pragma unroll
    for (int n = 0; n < 2; ++n) {
        const int m = 16 * (2 * wid + n) + r16;
        f16x8 h;
#pragma unroll
        for (int j = 0; j < 8; ++j) {
            float v = (j < 4) ? Cv_T[(4 * g + j) * NL_D + m]
                              : Dvy_T[(4 * g + (j & 3)) * NL_D + m];
            h[j] = (_Float16)(SC * v);
        }
        aB[n] = h;
    }
    f16x8 aK[5];                               // slot 0: [A;By] xy; 1+i: Bw chunk (wid+i)&3
    {
        f16x8 h;
#pragma unroll
        for (int j = 0; j < 8; ++j)
            h[j] = (_Float16)((j < 4) ? A_T[(4 * g + j) * ST_D + r16]
                                      : By_T[(4 * g + (j & 3)) * ST_D + r16]);
        aK[0] = h;
#pragma unroll
        for (int i = 0; i < 4; ++i) {
            const int s = (wid + i) & 3;
            f16x8 h2;
#pragma unroll
            for (int j = 0; j < 8; ++j)
                h2[j] = (_Float16)Bw_T[eperm(s, g, j) * ST_D + r16];
            aK[1 + i] = h2;
        }
    }
    f16x8 aU[5];                               // u (wave 1 only), chunk-rotated
    if (wid == 1) {
        f16x8 h;
#pragma unroll
        for (int j = 0; j < 8; ++j) {
            float v = 0.f;
            if (r16 < OUT_D)
                v = (j < 4) ? Cu_T[(4 * g + j) * OUT_D + r16]
                            : Duy_T[(4 * g + (j & 3)) * OUT_D + r16];
            h[j] = (_Float16)v;
        }
        aU[0] = h;
#pragma unroll
        for (int i = 0; i < 4; ++i) {
            const int s = (wid + i) & 3;
            f16x8 h2;
#pragma unroll
            for (int j = 0; j < 8; ++j)
                h2[j] = (_Float16)((r16 < OUT_D) ? Duw_T[eperm(s, g, j) * OUT_D + r16] : 0.f);
            aU[1 + i] = h2;
        }
    } else {
#pragma unroll
        for (int s = 0; s < 5; ++s) aU[s] = __builtin_bit_cast(f16x8, z4);
    }

    // ---- lane-local state: x[4g+q] of batch row `row` ----
    f32x4 xb = *(const f32x4*)(x0 + row * ST_D + 4 * g);

    f16x8 f0, f1, f2, f3;                      // w B-fragments, slots 0..3 (0=own)
    int cur = 0;
    char* const xbase = &xch[0][0][0];
    const int loff = lane * 16;

    auto tanh4 = [&](f32x4 t) -> f32x4 {       // arg already 2*log2(e)*a
        f32x4 o;
#pragma unroll
        for (int q = 0; q < 4; ++q)
            o[q] = fmaf(-2.0f, __builtin_amdgcn_rcpf(1.0f + __builtin_amdgcn_exp2f(t[q])), 1.0f);
        return o;
    };

    auto fpi = [&](int niter, f32x4 bias0, f32x4 bias1) {
#pragma unroll 1
        for (int it = 0; it < niter; ++it) {
            // chain A: slots 0,1 (own first: zero wait); chain B: slots 2,3
            f32x4 c00 = MFMA16(aD[0][0], f0, bias0);
            f32x4 c10 = MFMA16(aD[1][0], f0, bias1);
            f32x4 c01 = MFMA16(aD[0][2], f2, z4);
            f32x4 c11 = MFMA16(aD[1][2], f2, z4);
            c00 = MFMA16(aD[0][1], f1, c00);
            c10 = MFMA16(aD[1][1], f1, c10);
            c01 = MFMA16(aD[0][3], f3, c01);
            c11 = MFMA16(aD[1][3], f3, c11);
            f32x4 v0 = tanh4(c00 + c01);       // tile 2wid
            f32x4 v1 = tanh4(c10 + c11);       // tile 2wid+1
            i32x4 own;                         // == B-chunk `wid` for this lane
            own[0] = PK(v0[0], v0[1]);
            own[1] = PK(v0[2], v0[3]);
            own[2] = PK(v1[0], v1[1]);
            own[3] = PK(v1[2], v1[3]);
            char* nb = xbase + (cur ^ 1) * 4096;
            *(i32x4*)(nb + wid * 1024 + loff) = own;
            __syncthreads();
            f0 = __builtin_bit_cast(f16x8, own);          // own chunk: no LDS
            f1 = *(const f16x8*)(nb + c1 * 1024 + loff);  // foreign chunks
            f2 = *(const f16x8*)(nb + c2 * 1024 + loff);
            f3 = *(const f16x8*)(nb + c3 * 1024 + loff);
            cur ^= 1;
        }
    };

#pragma unroll 1
    for (int t = 0; t < T_STEPS; ++t) {
        f32x4 yb = *(const f32x4*)(obs + (row * T_STEPS + t) * IN_D + 4 * g);
        const int yw2 = PK(yb[0], yb[1]);
        const int yw3 = PK(yb[2], yb[3]);
        f0 = f1 = f2 = f3 = __builtin_bit_cast(f16x8, z4);   // w_init = 0
        f32x4 k1 = z4, k2 = z4, k3 = z4, k4 = z4;
        f32x4 xc = xb;

#pragma unroll
        for (int st = 0; st < 4; ++st) {
            i32x4 bxyw;
            bxyw[0] = PK(xc[0], xc[1]);
            bxyw[1] = PK(xc[2], xc[3]);
            bxyw[2] = yw2;
            bxyw[3] = yw3;
            f16x8 bXY = __builtin_bit_cast(f16x8, bxyw);
            f32x4 bias0 = MFMA16(aB[0], bXY, z4);
            f32x4 bias1 = MFMA16(aB[1], bXY, z4);
            fpi(st ? 5 : 30, bias0, bias1);
            // k epilogue — redundant on all waves keeps x replicated, no barrier
            f32x4 e0 = MFMA16(aK[0], bXY, z4);
            e0 = MFMA16(aK[1], f0, e0);
            e0 = MFMA16(aK[2], f1, e0);
            f32x4 e1 = MFMA16(aK[3], f2, z4);
            e1 = MFMA16(aK[4], f3, e1);
            f32x4 kc = e0 + e1;
            if (st == 0) {
                if (wid == 1) {                // u = x@Cu + w1@Duw + y@Duy
                    f32x4 u0 = MFMA16(aU[0], bXY, z4);
                    u0 = MFMA16(aU[1], f0, u0);
                    u0 = MFMA16(aU[2], f1, u0);
                    f32x4 u1 = MFMA16(aU[3], f2, z4);
                    u1 = MFMA16(aU[4], f3, u1);
                    f32x4 uc = u0 + u1;        // lane holds u[4g+q][row]
                    if (g < 2) {
                        float* op = out + (row * T_STEPS + t) * OUT_C + 4 * g;
                        op[0] = uc[0]; op[1] = uc[1]; op[2] = uc[2]; op[3] = uc[3];
                    }
                }
                k1 = kc;
#pragma unroll
                for (int q = 0; q < 4; ++q) xc[q] = fmaf(0.5f * DT_F, k1[q], xb[q]);
            } else if (st == 1) {
                k2 = kc;
#pragma unroll
                for (int q = 0; q < 4; ++q) xc[q] = fmaf(0.5f * DT_F, k2[q], xb[q]);
            } else if (st == 2) {
                k3 = kc;
#pragma unroll
                for (int q = 0; q < 4; ++q) xc[q] = fmaf(DT_F, k3[q], xb[q]);
            } else {
                k4 = kc;
#pragma unroll
                for (int q = 0; q < 4; ++q)
                    xb[q] = fmaf(DT_F / 6.0f,
                                 k1[q] + 2.0f * k2[q] + 2.0f * k3[q] + k4[q], xb[q]);
            }
        }
    }
}

// ---- value baseline MLP + log_std broadcast (unchanged, passes) ----
__device__ __forceinline__ float fast_tanh(float a) {
    float e = __expf(2.0f * a);
    return 1.0f - 2.0f / (e + 1.0f);
}

__global__ __launch_bounds__(256) void mlp_kernel(
    const float* __restrict__ obs, const float* __restrict__ log_stds,
    const float* __restrict__ W1, const float* __restrict__ b1,
    const float* __restrict__ W2, const float* __restrict__ b2,
    const float* __restrict__ W3, const float* __restrict__ b3,
    float* __restrict__ out) {
    __shared__ float sW1[IN_D * H_D];
    __shared__ float sW2[H_D * H_D];
    __shared__ float sb1[H_D], sb2[H_D], sW3[H_D], sls[OUT_D];
    __shared__ float sb3;
    const int tid = threadIdx.x;
    for (int i = tid; i < IN_D * H_D; i += 256) sW1[i] = W1[i];
    for (int i = tid; i < H_D * H_D; i += 256) sW2[i] = W2[i];
    if (tid < H_D) { sb1[tid] = b1[tid]; sb2[tid] = b2[tid]; sW3[tid] = W3[tid]; }
    if (tid < OUT_D) sls[tid] = log_stds[tid];
    if (tid == 0) sb3 = b3[0];
    __syncthreads();

    const int bt = blockIdx.x * 256 + tid;
    if (bt >= B_TOT * T_STEPS) return;

    float o[IN_D];
#pragma unroll
    for (int i = 0; i < IN_D; ++i) o[i] = obs[bt * IN_D + i];

    float h1[H_D];
#pragma unroll
    for (int h = 0; h < H_D; ++h) {
        float a = sb1[h];
#pragma unroll
        for (int i = 0; i < IN_D; ++i) a = fmaf(o[i], sW1[i * H_D + h], a);
        h1[h] = fast_tanh(a);
    }
    float v = sb3;
#pragma unroll
    for (int h = 0; h < H_D; ++h) {
        float a = sb2[h];
#pragma unroll
        for (int i = 0; i < H_D; ++i) a = fmaf(h1[i], sW2[i * H_D + h], a);
        v = fmaf(fast_tanh(a), sW3[h], v);
    }

    float* o17 = out + bt * OUT_C;
#pragma unroll
    for (int q = 0; q < OUT_D; ++q) o17[OUT_D + q] = sls[q];
    o17[16] = v;
}

extern "C" void kernel_launch(void* const* d_in, const int* in_sizes, int n_in,
                              void* d_out, int out_size, void* d_ws, size_t ws_size,
                              hipStream_t stream) {
    const float* obs      = (const float*)d_in[0];
    const float* x0       = (const float*)d_in[1];
    const float* A_T      = (const float*)d_in[2];
    const float* Bw_T     = (const float*)d_in[3];
    const float* By_T     = (const float*)d_in[4];
    const float* Cv_T     = (const float*)d_in[5];
    const float* Dvw_T    = (const float*)d_in[6];
    const float* Dvy_T    = (const float*)d_in[7];
    const float* Cu_T     = (const float*)d_in[8];
    const float* Duw_T    = (const float*)d_in[9];
    const float* Duy_T    = (const float*)d_in[10];
    const float* log_stds = (const float*)d_in[11];
    const float* W1       = (const float*)d_in[12];
    const float* b1       = (const float*)d_in[13];
    const float* W2       = (const float*)d_in[14];
    const float* b2       = (const float*)d_in[15];
    const float* W3       = (const float*)d_in[16];
    const float* b3       = (const float*)d_in[17];
    float* out = (float*)d_out;

    rinn_fpi<<<dim3(B_TOT / 16), dim3(256), 0, stream>>>(
        obs, x0, A_T, Bw_T, By_T, Cv_T, Dvw_T, Dvy_T, Cu_T, Duw_T, Duy_T, out);
    mlp_kernel<<<dim3((B_TOT * T_STEPS + 255) / 256), dim3(256), 0, stream>>>(
        obs, log_stds, W1, b1, W2, b2, W3, b3, out);
}

// Round 13
// 395.959 us; speedup vs baseline: 1.0853x; 1.0853x over previous
//
#include <hip/hip_runtime.h>

// DissipativeRINN — TRANSPOSED fp16 MFMA (M=w-elements, N=batch rows),
// 8-wave fine split: wave i owns M-tile i (16 w-elements).
// 128 blocks x 8 waves (512 thr); block = 16 batch rows.
// Per iter per wave: 4 MFMA (two 2-deep chains + add), 4-value tanh,
// 1 ds_write_b64 (its half of chunk wid>>1), barrier, 4 ds_read_b128.
// eperm identity: packed tanh outputs ARE the B-fragments (no reshuffle).
// 2 waves/SIMD interleave chain stalls between barriers.

typedef _Float16 f16x8 __attribute__((ext_vector_type(8)));
typedef float f32x4 __attribute__((ext_vector_type(4)));
typedef int i32x2 __attribute__((ext_vector_type(2)));

constexpr int B_TOT   = 2048;
constexpr int T_STEPS = 32;
constexpr int IN_D    = 16;
constexpr int ST_D    = 16;
constexpr int NL_D    = 128;
constexpr int OUT_D   = 8;
constexpr int H_D     = 64;
constexpr int OUT_C   = 17;
constexpr float DT_F  = 0.01f;
constexpr float SC    = 2.8853900817779268f;   // 2*log2(e)

// k-position p = 32s + 8g + j  <->  w-element e (bijective; bit-disjoint)
__device__ __forceinline__ int eperm(int s, int g, int j) {
    return 32 * s + 16 * (j >> 2) + 4 * g + (j & 3);
}

#define MFMA16(A, B, C) __builtin_amdgcn_mfma_f32_16x16x32_f16((A), (B), (C), 0, 0, 0)
#define PK(a, b) __builtin_bit_cast(int, __builtin_amdgcn_cvt_pkrtz((a), (b)))

__global__ __launch_bounds__(512, 1) void rinn_fpi(
    const float* __restrict__ obs, const float* __restrict__ x0,
    const float* __restrict__ A_T, const float* __restrict__ Bw_T,
    const float* __restrict__ By_T, const float* __restrict__ Cv_T,
    const float* __restrict__ Dvw_T, const float* __restrict__ Dvy_T,
    const float* __restrict__ Cu_T, const float* __restrict__ Duw_T,
    const float* __restrict__ Duy_T, float* __restrict__ out)
{
    __shared__ __align__(16) char xch[2][4][1024];   // [dbuf][chunk][lane*16B]
    const int tid  = threadIdx.x;
    const int wid  = tid >> 6;                 // owns M-tile wid (0..7)
    const int lane = tid & 63;
    const int g    = lane >> 4;
    const int r16  = lane & 15;
    const int row  = blockIdx.x * 16 + r16;    // this lane's batch row
    const f32x4 z4 = {0.f, 0.f, 0.f, 0.f};

    // ---- A fragments for tile wid. Dvw_T[in][out], SC pre-scaled ----
    f16x8 aD[4];                               // [k-chunk]
#pragma unroll
    for (int s = 0; s < 4; ++s) {
        f16x8 h;
#pragma unroll
        for (int j = 0; j < 8; ++j)
            h[j] = (_Float16)(SC * Dvw_T[eperm(s, g, j) * NL_D + 16 * wid + r16]);
        aD[s] = h;
    }
    f16x8 aB;                                  // [Cv;Dvy] over xy (K=32), x SC
    {
        const int m = 16 * wid + r16;
        f16x8 h;
#pragma unroll
        for (int j = 0; j < 8; ++j) {
            float v = (j < 4) ? Cv_T[(4 * g + j) * NL_D + m]
                              : Dvy_T[(4 * g + (j & 3)) * NL_D + m];
            h[j] = (_Float16)(SC * v);
        }
        aB = h;
    }
    f16x8 aK[5];                               // slot 0: [A;By] xy; 1+s: Bw chunk s
    {
        f16x8 h;
#pragma unroll
        for (int j = 0; j < 8; ++j)
            h[j] = (_Float16)((j < 4) ? A_T[(4 * g + j) * ST_D + r16]
                                      : By_T[(4 * g + (j & 3)) * ST_D + r16]);
        aK[0] = h;
#pragma unroll
        for (int s = 0; s < 4; ++s) {
            f16x8 h2;
#pragma unroll
            for (int j = 0; j < 8; ++j)
                h2[j] = (_Float16)Bw_T[eperm(s, g, j) * ST_D + r16];
            aK[1 + s] = h2;
        }
    }
    f16x8 aU[5];                               // u (wave 1 only; m'=r16<8 real)
    if (wid == 1) {
        f16x8 h;
#pragma unroll
        for (int j = 0; j < 8; ++j) {
            float v = 0.f;
            if (r16 < OUT_D)
                v = (j < 4) ? Cu_T[(4 * g + j) * OUT_D + r16]
                            : Duy_T[(4 * g + (j & 3)) * OUT_D + r16];
            h[j] = (_Float16)v;
        }
        aU[0] = h;
#pragma unroll
        for (int s = 0; s < 4; ++s) {
            f16x8 h2;
#pragma unroll
            for (int j = 0; j < 8; ++j)
                h2[j] = (_Float16)((r16 < OUT_D) ? Duw_T[eperm(s, g, j) * OUT_D + r16] : 0.f);
            aU[1 + s] = h2;
        }
    } else {
#pragma unroll
        for (int s = 0; s < 5; ++s) aU[s] = __builtin_bit_cast(f16x8, z4);
    }

    // ---- lane-local state: x[4g+q] of batch row `row` (replicated per wave) ----
    f32x4 xb = *(const f32x4*)(x0 + row * ST_D + 4 * g);

    f16x8 f0, f1, f2, f3;                      // w B-fragments, chunks 0..3
    int cur = 0;
    char* const xbase = &xch[0][0][0];
    const int loff = lane * 16;
    const int woff = (wid >> 1) * 1024 + loff + (wid & 1) * 8;  // own half-chunk

    auto tanh4 = [&](f32x4 t) -> f32x4 {       // arg already 2*log2(e)*a
        f32x4 o;
#pragma unroll
        for (int q = 0; q < 4; ++q)
            o[q] = fmaf(-2.0f, __builtin_amdgcn_rcpf(1.0f + __builtin_amdgcn_exp2f(t[q])), 1.0f);
        return o;
    };

    auto fpi = [&](int niter, f32x4 bias) {
#pragma unroll 1
        for (int it = 0; it < niter; ++it) {
            // two 2-deep chains + add (same accumulation order as R12)
            f32x4 ca = MFMA16(aD[0], f0, bias);
            f32x4 cb = MFMA16(aD[2], f2, z4);
            ca = MFMA16(aD[1], f1, ca);
            cb = MFMA16(aD[3], f3, cb);
            f32x4 v = tanh4(ca + cb);          // tile wid: elems 16*wid + 4g + q
            i32x2 own;                         // half of B-chunk wid>>1
            own[0] = PK(v[0], v[1]);
            own[1] = PK(v[2], v[3]);
            char* nb = xbase + (cur ^ 1) * 4096;
            *(i32x2*)(nb + woff) = own;
            __syncthreads();
            f0 = *(const f16x8*)(nb + 0 * 1024 + loff);
            f1 = *(const f16x8*)(nb + 1 * 1024 + loff);
            f2 = *(const f16x8*)(nb + 2 * 1024 + loff);
            f3 = *(const f16x8*)(nb + 3 * 1024 + loff);
            cur ^= 1;
        }
    };

#pragma unroll 1
    for (int t = 0; t < T_STEPS; ++t) {
        f32x4 yb = *(const f32x4*)(obs + (row * T_STEPS + t) * IN_D + 4 * g);
        const int yw2 = PK(yb[0], yb[1]);
        const int yw3 = PK(yb[2], yb[3]);
        f0 = f1 = f2 = f3 = __builtin_bit_cast(f16x8, z4);   // w_init = 0
        f32x4 k1 = z4, k2 = z4, k3 = z4, k4 = z4;
        f32x4 xc = xb;

#pragma unroll
        for (int st = 0; st < 4; ++st) {
            i32x2 bxl;                         // B-fragment of [x|y] (K=32)
            bxl[0] = PK(xc[0], xc[1]);
            bxl[1] = PK(xc[2], xc[3]);
            int bxyw[4] = {bxl[0], bxl[1], yw2, yw3};
            f16x8 bXY;
            memcpy(&bXY, bxyw, 16);
            f32x4 bias = MFMA16(aB, bXY, z4);
            fpi(st ? 5 : 30, bias);
            // k epilogue — redundant on all waves keeps x replicated, no barrier
            f32x4 e0 = MFMA16(aK[0], bXY, z4);
            e0 = MFMA16(aK[1], f0, e0);
            e0 = MFMA16(aK[2], f1, e0);
            f32x4 e1 = MFMA16(aK[3], f2, z4);
            e1 = MFMA16(aK[4], f3, e1);
            f32x4 kc = e0 + e1;
            if (st == 0) {
                if (wid == 1) {                // u = x@Cu + w1@Duw + y@Duy
                    f32x4 u0 = MFMA16(aU[0], bXY, z4);
                    u0 = MFMA16(aU[1], f0, u0);
                    u0 = MFMA16(aU[2], f1, u0);
                    f32x4 u1 = MFMA16(aU[3], f2, z4);
                    u1 = MFMA16(aU[4], f3, u1);
                    f32x4 uc = u0 + u1;        // lane holds u[4g+q][row]
                    if (g < 2) {
                        float* op = out + (row * T_STEPS + t) * OUT_C + 4 * g;
                        op[0] = uc[0]; op[1] = uc[1]; op[2] = uc[2]; op[3] = uc[3];
                    }
                }
                k1 = kc;
#pragma unroll
                for (int q = 0; q < 4; ++q) xc[q] = fmaf(0.5f * DT_F, k1[q], xb[q]);
            } else if (st == 1) {
                k2 = kc;
#pragma unroll
                for (int q = 0; q < 4; ++q) xc[q] = fmaf(0.5f * DT_F, k2[q], xb[q]);
            } else if (st == 2) {
                k3 = kc;
#pragma unroll
                for (int q = 0; q < 4; ++q) xc[q] = fmaf(DT_F, k3[q], xb[q]);
            } else {
                k4 = kc;
#pragma unroll
                for (int q = 0; q < 4; ++q)
                    xb[q] = fmaf(DT_F / 6.0f,
                                 k1[q] + 2.0f * k2[q] + 2.0f * k3[q] + k4[q], xb[q]);
            }
        }
    }
}

// ---- value baseline MLP + log_std broadcast (unchanged, passes) ----
__device__ __forceinline__ float fast_tanh(float a) {
    float e = __expf(2.0f * a);
    return 1.0f - 2.0f / (e + 1.0f);
}

__global__ __launch_bounds__(256) void mlp_kernel(
    const float* __restrict__ obs, const float* __restrict__ log_stds,
    const float* __restrict__ W1, const float* __restrict__ b1,
    const float* __restrict__ W2, const float* __restrict__ b2,
    const float* __restrict__ W3, const float* __restrict__ b3,
    float* __restrict__ out) {
    __shared__ float sW1[IN_D * H_D];
    __shared__ float sW2[H_D * H_D];
    __shared__ float sb1[H_D], sb2[H_D], sW3[H_D], sls[OUT_D];
    __shared__ float sb3;
    const int tid = threadIdx.x;
    for (int i = tid; i < IN_D * H_D; i += 256) sW1[i] = W1[i];
    for (int i = tid; i < H_D * H_D; i += 256) sW2[i] = W2[i];
    if (tid < H_D) { sb1[tid] = b1[tid]; sb2[tid] = b2[tid]; sW3[tid] = W3[tid]; }
    if (tid < OUT_D) sls[tid] = log_stds[tid];
    if (tid == 0) sb3 = b3[0];
    __syncthreads();

    const int bt = blockIdx.x * 256 + tid;
    if (bt >= B_TOT * T_STEPS) return;

    float o[IN_D];
#pragma unroll
    for (int i = 0; i < IN_D; ++i) o[i] = obs[bt * IN_D + i];

    float h1[H_D];
#pragma unroll
    for (int h = 0; h < H_D; ++h) {
        float a = sb1[h];
#pragma unroll
        for (int i = 0; i < IN_D; ++i) a = fmaf(o[i], sW1[i * H_D + h], a);
        h1[h] = fast_tanh(a);
    }
    float v = sb3;
#pragma unroll
    for (int h = 0; h < H_D; ++h) {
        float a = sb2[h];
#pragma unroll
        for (int i = 0; i < H_D; ++i) a = fmaf(h1[i], sW2[i * H_D + h], a);
        v = fmaf(fast_tanh(a), sW3[h], v);
    }

    float* o17 = out + bt * OUT_C;
#pragma unroll
    for (int q = 0; q < OUT_D; ++q) o17[OUT_D + q] = sls[q];
    o17[16] = v;
}

extern "C" void kernel_launch(void* const* d_in, const int* in_sizes, int n_in,
                              void* d_out, int out_size, void* d_ws, size_t ws_size,
                              hipStream_t stream) {
    const float* obs      = (const float*)d_in[0];
    const float* x0       = (const float*)d_in[1];
    const float* A_T      = (const float*)d_in[2];
    const float* Bw_T     = (const float*)d_in[3];
    const float* By_T     = (const float*)d_in[4];
    const float* Cv_T     = (const float*)d_in[5];
    const float* Dvw_T    = (const float*)d_in[6];
    const float* Dvy_T    = (const float*)d_in[7];
    const float* Cu_T     = (const float*)d_in[8];
    const float* Duw_T    = (const float*)d_in[9];
    const float* Duy_T    = (const float*)d_in[10];
    const float* log_stds = (const float*)d_in[11];
    const float* W1       = (const float*)d_in[12];
    const float* b1       = (const float*)d_in[13];
    const float* W2       = (const float*)d_in[14];
    const float* b2       = (const float*)d_in[15];
    const float* W3       = (const float*)d_in[16];
    const float* b3       = (const float*)d_in[17];
    float* out = (float*)d_out;

    rinn_fpi<<<dim3(B_TOT / 16), dim3(512), 0, stream>>>(
        obs, x0, A_T, Bw_T, By_T, Cv_T, Dvw_T, Dvy_T, Cu_T, Duw_T, Duy_T, out);
    mlp_kernel<<<dim3((B_TOT * T_STEPS + 255) / 256), dim3(256), 0, stream>>>(
        obs, log_stds, W1, b1, W2, b2, W3, b3, out);
}